// Round 1
// baseline (5946.607 us; speedup 1.0000x reference)
//
#include <hip/hip_runtime.h>
#include <hip/hip_fp16.h>

typedef _Float16 f16;
typedef _Float16 f16x2 __attribute__((ext_vector_type(2)));
typedef _Float16 f16x8 __attribute__((ext_vector_type(8)));
typedef float f32x4 __attribute__((ext_vector_type(4)));

#define B_    32
#define T_    2048
#define E_    512
#define H_    256
#define G4_   1024
#define NTOK  (B_*T_)
#define VOCAB_ 50257

// ---------------- workspace layout (bytes) ----------------
// xg      f16  [NTOK][1024]   134217728
// wih16   f16  [1024][512]      1048576
// wreg    u32  [96][1024]        393216
// wlds    u4   [8][1024]         131072
// bsum    f32  [1024]              4096
// pool    f32  [32][256]          32768
// lens    f32  [32]                 128
static const size_t WS_XG   = 0;
static const size_t WS_WIH  = 134217728ull;
static const size_t WS_WREG = 135266304ull;
static const size_t WS_WLDS = 135659520ull;
static const size_t WS_BSUM = 135790592ull;
static const size_t WS_POOL = 135794688ull;
static const size_t WS_LENS = 135827456ull;

__device__ __forceinline__ unsigned pack2f(float a, float b) {
    f16x2 h; h.x = (f16)a; h.y = (f16)b;
    return __builtin_bit_cast(unsigned, h);
}

__device__ __forceinline__ float fdot2u(unsigned a, unsigned b, float c) {
#if __has_builtin(__builtin_amdgcn_fdot2)
    return __builtin_amdgcn_fdot2(__builtin_bit_cast(f16x2, a),
                                  __builtin_bit_cast(f16x2, b), c, false);
#else
    f16x2 av = __builtin_bit_cast(f16x2, a), bv = __builtin_bit_cast(f16x2, b);
    return c + (float)av.x * (float)bv.x + (float)av.y * (float)bv.y;
#endif
}

__device__ __forceinline__ float sigm(float v) {
    return 1.f / (1.f + exp2f(-1.44269504f * v));
}
__device__ __forceinline__ float tanhr(float v) {
    float t = exp2f(-2.88539008f * fabsf(v));   // e^(-2|v|)
    float r = (1.f - t) / (1.f + t);
    return v < 0.f ? -r : r;
}

// detect int64 tokens passed through an int32 view (high dwords are 0)
__device__ __forceinline__ int detect64(const int* x) {
    return (x[1] == 0 && x[3] == 0 && x[5] == 0) ? 1 : 0;
}

// ---------------- prep: f32->f16 weight conversions + layouts ----------------
__global__ void prep_k(const float* __restrict__ w_ih, const float* __restrict__ w_hh,
                       const float* __restrict__ b_ih, const float* __restrict__ b_hh,
                       f16* __restrict__ wih16, unsigned* __restrict__ wreg,
                       uint4* __restrict__ wlds, float* __restrict__ bsum)
{
    const int gid = blockIdx.x * blockDim.x + threadIdx.x;
    const int stride = gridDim.x * blockDim.x;
    for (int i = gid; i < G4_*E_; i += stride) wih16[i] = (f16)w_ih[i];
    for (int i = gid; i < G4_; i += stride) bsum[i] = b_ih[i] + b_hh[i];
    // register-resident w_hh part: thread t owns rows {64w+r16*4+q}, k in [kc*64, kc*64+48)
    for (int i = gid; i < 96*1024; i += stride) {
        const int ii = i >> 10, t = i & 1023;
        const int w = t >> 6, lane = t & 63, kc = lane >> 4, r16 = lane & 15;
        const int q = ii / 24, pp = ii % 24;
        const int row = w*64 + r16*4 + q;
        const int k = kc*64 + pp*2;
        wreg[i] = pack2f(w_hh[row*256 + k], w_hh[row*256 + k + 1]);
    }
    // LDS-resident w_hh part: k in [kc*64+48, kc*64+64), c = q*2+khalf
    for (int i = gid; i < 8*1024; i += stride) {
        const int c = i >> 10, t = i & 1023;
        const int w = t >> 6, lane = t & 63, kc = lane >> 4, r16 = lane & 15;
        const int q = c >> 1, khh = c & 1;
        const int row = w*64 + r16*4 + q;
        const int kb = kc*64 + 48 + khh*8;
        uint4 v;
        v.x = pack2f(w_hh[row*256 + kb + 0], w_hh[row*256 + kb + 1]);
        v.y = pack2f(w_hh[row*256 + kb + 2], w_hh[row*256 + kb + 3]);
        v.z = pack2f(w_hh[row*256 + kb + 4], w_hh[row*256 + kb + 5]);
        v.w = pack2f(w_hh[row*256 + kb + 6], w_hh[row*256 + kb + 7]);
        wlds[i] = v;
    }
}

// ---------------- GEMM: xg = f16(emb[x]) @ f16(w_ih)^T + bsum ----------------
__global__ __launch_bounds__(256) void gemm_xg_k(
    const int* __restrict__ x, const float* __restrict__ emb,
    const f16* __restrict__ wih, const float* __restrict__ bsum,
    f16* __restrict__ xg)
{
    __shared__ f16 As[128*32];   // [token_row][k], stride 32
    __shared__ f16 Bs[128*32];   // [gate_row][k], stride 32
    const int tid = threadIdx.x;
    const int bid = blockIdx.x;
    const int mt = bid >> 3, nt = bid & 7;          // 512 m-tiles x 8 n-tiles
    const int wv = tid >> 6, lane = tid & 63;
    const int wm = wv & 1, wn = wv >> 1;
    const int ml = lane & 15, kg = lane >> 4;
    const int is64 = detect64(x);
    const int r = tid >> 1, kh = tid & 1;
    int tok = x[(mt*128 + r) << is64];
    tok = tok < 0 ? 0 : (tok >= VOCAB_ ? VOCAB_ - 1 : tok);
    const float* arow = emb + (size_t)tok * E_ + kh*16;
    const f16*   brow = wih + (size_t)(nt*128 + r) * E_ + kh*16;

    f32x4 acc[4][4] = {};
    for (int kk = 0; kk < 16; ++kk) {
        const int k0 = kk * 32;
        float4 a0 = *(const float4*)(arow + k0 + 0);
        float4 a1 = *(const float4*)(arow + k0 + 4);
        float4 a2 = *(const float4*)(arow + k0 + 8);
        float4 a3 = *(const float4*)(arow + k0 + 12);
        uint4 bu0 = *(const uint4*)(brow + k0);
        uint4 bu1 = *(const uint4*)(brow + k0 + 8);
        uint4 au0, au1;
        au0.x = pack2f(a0.x, a0.y); au0.y = pack2f(a0.z, a0.w);
        au0.z = pack2f(a1.x, a1.y); au0.w = pack2f(a1.z, a1.w);
        au1.x = pack2f(a2.x, a2.y); au1.y = pack2f(a2.z, a2.w);
        au1.z = pack2f(a3.x, a3.y); au1.w = pack2f(a3.z, a3.w);
        __syncthreads();
        *(uint4*)(&As[r*32 + kh*16 + 0]) = au0;
        *(uint4*)(&As[r*32 + kh*16 + 8]) = au1;
        *(uint4*)(&Bs[r*32 + kh*16 + 0]) = bu0;
        *(uint4*)(&Bs[r*32 + kh*16 + 8]) = bu1;
        __syncthreads();
        f16x8 af[4], bf[4];
        #pragma unroll
        for (int i = 0; i < 4; ++i) {
            af[i] = *(const f16x8*)(&As[(wm*64 + i*16 + ml)*32 + kg*8]);
            bf[i] = *(const f16x8*)(&Bs[(wn*64 + i*16 + ml)*32 + kg*8]);
        }
        #pragma unroll
        for (int i = 0; i < 4; ++i)
            #pragma unroll
            for (int j = 0; j < 4; ++j)
                acc[i][j] = __builtin_amdgcn_mfma_f32_16x16x32_f16(af[i], bf[j], acc[i][j], 0, 0, 0);
    }
    #pragma unroll
    for (int j = 0; j < 4; ++j) {
        const int gc = nt*128 + wn*64 + j*16 + ml;
        const float bs = bsum[gc];
        #pragma unroll
        for (int i = 0; i < 4; ++i) {
            #pragma unroll
            for (int q = 0; q < 4; ++q) {
                const int gr = mt*128 + wm*64 + i*16 + kg*4 + q;
                xg[(size_t)gr*G4_ + gc] = (f16)(acc[i][j][q] + bs);
            }
        }
    }
}

// ---------------- recurrence: 1 block = 1 batch, weights in VGPR+LDS ----------------
__global__ __launch_bounds__(1024) void recur_k(
    const int* __restrict__ x, const f16* __restrict__ xg,
    const unsigned* __restrict__ wreg_g, const uint4* __restrict__ wlds_g,
    float* __restrict__ pool, float* __restrict__ lens)
{
    extern __shared__ char smem[];
    char*  wlds = smem;                       // 131072: per-thread 128B, XOR-swizzled
    float* gbuf = (float*)(smem + 131072);    // 4096: activated gates
    char*  hbB  = smem + 135168;              // 576: h as f16 pairs, 144B per k-chunk
    const int tid = threadIdx.x, b = blockIdx.x;
    const int wv = tid >> 6, lane = tid & 63, kc = lane >> 4, r16 = lane & 15;
    const int is64 = detect64(x);

    unsigned wr[96];
    #pragma unroll
    for (int i = 0; i < 96; ++i) wr[i] = wreg_g[i*1024 + tid];
    #pragma unroll
    for (int c = 0; c < 8; ++c)
        *(uint4*)(wlds + tid*128 + ((c ^ (tid & 7)) * 16)) = wlds_g[c*1024 + tid];
    if (tid < 144) ((unsigned*)hbB)[tid] = 0u;

    float cst = 0.f, pooled = 0.f; int len = 0;
    const int* xrow = x + (((size_t)b*T_) << is64);
    const f16* xgrow = xg + (size_t)b*T_*G4_;
    const int g0 = wv*64 + r16*4;
    const int gtype = wv >> 2;                // 0:i 1:f 2:g 3:o  (wave-uniform)
    const char* hc = hbB + kc*144;
    __syncthreads();

    for (int t = 0; t < T_; ++t) {
        // xg prefetch (independent of h -> overlaps the dot phase)
        uint2 xv = *(const uint2*)((const char*)xgrow + ((size_t)t*G4_ + g0)*2);
        float p[4] = {0.f, 0.f, 0.f, 0.f};
        // register-resident weights: 4 rows x 48 k
        #pragma unroll
        for (int cc = 0; cc < 6; ++cc) {
            uint4 hp = *(const uint4*)(hc + cc*16);
            #pragma unroll
            for (int q = 0; q < 4; ++q) {
                p[q] = fdot2u(wr[q*24 + cc*4 + 0], hp.x, p[q]);
                p[q] = fdot2u(wr[q*24 + cc*4 + 1], hp.y, p[q]);
                p[q] = fdot2u(wr[q*24 + cc*4 + 2], hp.z, p[q]);
                p[q] = fdot2u(wr[q*24 + cc*4 + 3], hp.w, p[q]);
            }
        }
        // LDS-resident weights: 4 rows x 16 k
        #pragma unroll
        for (int khh = 0; khh < 2; ++khh) {
            uint4 hp = *(const uint4*)(hc + 96 + khh*16);
            #pragma unroll
            for (int q = 0; q < 4; ++q) {
                uint4 w4 = *(const uint4*)(wlds + tid*128 + ((((q<<1)|khh) ^ (tid & 7)) * 16));
                p[q] = fdot2u(w4.x, hp.x, p[q]);
                p[q] = fdot2u(w4.y, hp.y, p[q]);
                p[q] = fdot2u(w4.z, hp.z, p[q]);
                p[q] = fdot2u(w4.w, hp.w, p[q]);
            }
        }
        // reduce over k-chunks (lane bits 4,5)
        #pragma unroll
        for (int q = 0; q < 4; ++q) {
            p[q] += __shfl_xor(p[q], 16);
            p[q] += __shfl_xor(p[q], 32);
        }
        if (kc == 0) {
            f16x2 x01 = __builtin_bit_cast(f16x2, xv.x);
            f16x2 x23 = __builtin_bit_cast(f16x2, xv.y);
            float a0 = p[0] + (float)x01.x;
            float a1 = p[1] + (float)x01.y;
            float a2 = p[2] + (float)x23.x;
            float a3 = p[3] + (float)x23.y;
            if (gtype == 2) { a0 = tanhr(a0); a1 = tanhr(a1); a2 = tanhr(a2); a3 = tanhr(a3); }
            else            { a0 = sigm(a0);  a1 = sigm(a1);  a2 = sigm(a2);  a3 = sigm(a3);  }
            *(float4*)(gbuf + g0) = make_float4(a0, a1, a2, a3);
        }
        __syncthreads();
        if (tid < 256) {
            float gi = gbuf[tid], gf = gbuf[tid+256], gg = gbuf[tid+512], go = gbuf[tid+768];
            cst = gf*cst + gi*gg;
            float hv = go * tanhr(cst);
            if (xrow[(size_t)t << is64] != 0) { pooled += hv; ++len; }
            *(f16*)(hbB + (tid>>6)*144 + (tid&63)*2) = (f16)hv;
        }
        __syncthreads();
    }
    if (tid < 256) pool[b*H_ + tid] = pooled;
    if (tid == 0) lens[b] = (float)len;
}

// ---------------- head: pooled mean -> relu(lin1) -> lin2 ----------------
__global__ __launch_bounds__(256) void head_k(
    const float* __restrict__ pool, const float* __restrict__ lens,
    const float* __restrict__ w1, const float* __restrict__ b1,
    const float* __restrict__ w2, const float* __restrict__ b2,
    float* __restrict__ out)
{
    __shared__ float pl[256];
    __shared__ float l1[512];
    const int b = blockIdx.x, tid = threadIdx.x;
    const float inv = 1.f / lens[b];
    pl[tid] = pool[b*256 + tid] * inv;
    __syncthreads();
    for (int o = tid; o < 512; o += 256) {
        const float4* wrow = (const float4*)(w1 + (size_t)o*256);
        float s = b1[o];
        #pragma unroll 8
        for (int k = 0; k < 64; ++k) {
            float4 wv = wrow[k];
            s += pl[k*4+0]*wv.x + pl[k*4+1]*wv.y + pl[k*4+2]*wv.z + pl[k*4+3]*wv.w;
        }
        l1[o] = fmaxf(s, 0.f);
    }
    __syncthreads();
    if (tid < 20) {
        const float4* wrow = (const float4*)(w2 + (size_t)tid*512);
        float s = b2[tid];
        #pragma unroll 8
        for (int k = 0; k < 128; ++k) {
            float4 wv = wrow[k];
            s += l1[k*4+0]*wv.x + l1[k*4+1]*wv.y + l1[k*4+2]*wv.z + l1[k*4+3]*wv.w;
        }
        out[b*20 + tid] = s;
    }
}

extern "C" void kernel_launch(void* const* d_in, const int* in_sizes, int n_in,
                              void* d_out, int out_size, void* d_ws, size_t ws_size,
                              hipStream_t stream) {
    (void)in_sizes; (void)n_in; (void)out_size; (void)ws_size;
    const int*   x    = (const int*)d_in[0];
    const float* emb  = (const float*)d_in[1];
    const float* w_ih = (const float*)d_in[2];
    const float* w_hh = (const float*)d_in[3];
    const float* b_ih = (const float*)d_in[4];
    const float* b_hh = (const float*)d_in[5];
    const float* w1   = (const float*)d_in[6];
    const float* b1   = (const float*)d_in[7];
    const float* w2   = (const float*)d_in[8];
    const float* b2   = (const float*)d_in[9];
    float* out = (float*)d_out;
    char* ws = (char*)d_ws;

    f16*      xg    = (f16*)(ws + WS_XG);
    f16*      wih16 = (f16*)(ws + WS_WIH);
    unsigned* wreg  = (unsigned*)(ws + WS_WREG);
    uint4*    wlds  = (uint4*)(ws + WS_WLDS);
    float*    bsum  = (float*)(ws + WS_BSUM);
    float*    pool  = (float*)(ws + WS_POOL);
    float*    lensb = (float*)(ws + WS_LENS);

    hipLaunchKernelGGL(prep_k, dim3(512), dim3(256), 0, stream,
                       w_ih, w_hh, b_ih, b_hh, wih16, wreg, wlds, bsum);
    hipLaunchKernelGGL(gemm_xg_k, dim3(4096), dim3(256), 0, stream,
                       x, emb, wih16, bsum, xg);
    hipLaunchKernelGGL(recur_k, dim3(32), dim3(1024), 135744, stream,
                       x, xg, wreg, wlds, pool, lensb);
    hipLaunchKernelGGL(head_k, dim3(32), dim3(256), 0, stream,
                       pool, lensb, w1, b1, w2, b2, out);
}

// Round 2
// 4967.178 us; speedup vs baseline: 1.1972x; 1.1972x over previous
//
#include <hip/hip_runtime.h>
#include <hip/hip_fp16.h>

typedef _Float16 f16;
typedef _Float16 f16x2 __attribute__((ext_vector_type(2)));
typedef _Float16 f16x8 __attribute__((ext_vector_type(8)));
typedef float f32x4 __attribute__((ext_vector_type(4)));

#define B_    32
#define T_    2048
#define E_    512
#define H_    256
#define G4_   1024
#define VOCAB_ 50257

// ---------------- workspace layout (bytes) ----------------
static const size_t WS_XG   = 0;            // f16 [65536][1024] = 134217728
static const size_t WS_WIH  = 134217728ull; // f16 [1024][512]   = 1048576
static const size_t WS_WREG = 135266304ull; // u32 [96][1024]    = 393216
static const size_t WS_WLDS = 135659520ull; // uint4 [16*8*64]   = 131072
static const size_t WS_BSUM = 135790592ull; // f32 [1024]
static const size_t WS_POOL = 135794688ull; // f32 [32][256]
static const size_t WS_LENS = 135827456ull; // f32 [32]

#define HB_OFF 131072      // h double-buffer offset inside dynamic LDS
#define LDS_BYTES (131072 + 1152)

__device__ __forceinline__ unsigned pack2f(float a, float b) {
    f16x2 h; h.x = (f16)a; h.y = (f16)b;
    return __builtin_bit_cast(unsigned, h);
}

__device__ __forceinline__ float fdot2u(unsigned a, unsigned b, float c) {
#if __has_builtin(__builtin_amdgcn_fdot2)
    return __builtin_amdgcn_fdot2(__builtin_bit_cast(f16x2, a),
                                  __builtin_bit_cast(f16x2, b), c, false);
#else
    f16x2 av = __builtin_bit_cast(f16x2, a), bv = __builtin_bit_cast(f16x2, b);
    return c + (float)av.x * (float)bv.x + (float)av.y * (float)bv.y;
#endif
}

__device__ __forceinline__ float sigm(float v) {
    return 1.f / (1.f + exp2f(-1.44269504f * v));
}
__device__ __forceinline__ float tanhr(float v) {
    float t = exp2f(-2.88539008f * fabsf(v));   // e^(-2|v|)
    float r = (1.f - t) / (1.f + t);
    return v < 0.f ? -r : r;
}

__device__ __forceinline__ int detect64(const int* x) {
    return (x[1] == 0 && x[3] == 0 && x[5] == 0) ? 1 : 0;
}

// ---------------- prep: weight conversions + recurrence layouts ----------------
// Thread mapping in recur: tid -> wv=tid>>6, lane=tid&63, kc=lane>>4, li=lane&15,
// j = wv*16+li. Thread owns rows {q*256+j, q=0..3}, k-range [kc*64, kc*64+64).
// Register part: k in [kc*64, kc*64+48): wr[q*24 + cc*4 + u] covers k=kc*64+cc*8+u*2.
// LDS part: k in [kc*64+48, kc*64+64): slot s=q*2+kh, 8 k's each.
__global__ void prep_k(const float* __restrict__ w_ih, const float* __restrict__ w_hh,
                       const float* __restrict__ b_ih, const float* __restrict__ b_hh,
                       f16* __restrict__ wih16, unsigned* __restrict__ wreg,
                       uint4* __restrict__ wlds, float* __restrict__ bsum)
{
    const int gid = blockIdx.x * blockDim.x + threadIdx.x;
    const int stride = gridDim.x * blockDim.x;
    for (int i = gid; i < G4_*E_; i += stride) wih16[i] = (f16)w_ih[i];
    for (int i = gid; i < G4_; i += stride) bsum[i] = b_ih[i] + b_hh[i];
    for (int i = gid; i < 96*1024; i += stride) {
        const int ii = i >> 10, t = i & 1023;
        const int wv = t >> 6, lane = t & 63, kc = lane >> 4, li = lane & 15;
        const int j = wv*16 + li;
        const int q = ii / 24, rem = ii % 24, cc = rem >> 2, u = rem & 3;
        const int row = q*256 + j;
        const int k = kc*64 + cc*8 + u*2;
        wreg[i] = pack2f(w_hh[row*256 + k], w_hh[row*256 + k + 1]);
    }
    for (int i = gid; i < 16*8*64; i += stride) {
        const int lane = i & 63, s = (i >> 6) & 7, wv = i >> 9;
        const int kc = lane >> 4, li = lane & 15;
        const int j = wv*16 + li;
        const int q = s >> 1, kh = s & 1;
        const int row = q*256 + j;
        const int kb = kc*64 + 48 + kh*8;
        uint4 v;
        v.x = pack2f(w_hh[row*256 + kb + 0], w_hh[row*256 + kb + 1]);
        v.y = pack2f(w_hh[row*256 + kb + 2], w_hh[row*256 + kb + 3]);
        v.z = pack2f(w_hh[row*256 + kb + 4], w_hh[row*256 + kb + 5]);
        v.w = pack2f(w_hh[row*256 + kb + 6], w_hh[row*256 + kb + 7]);
        wlds[i] = v;
    }
}

// ---------------- GEMM: xg[t][j*4+gt] = (f16(emb[x]) @ f16(w_ih)^T + bsum) permuted ----------------
__global__ __launch_bounds__(256) void gemm_xg_k(
    const int* __restrict__ x, const float* __restrict__ emb,
    const f16* __restrict__ wih, const float* __restrict__ bsum,
    f16* __restrict__ xg)
{
    __shared__ f16 As[128*32];
    __shared__ f16 Bs[128*32];
    const int tid = threadIdx.x;
    const int bid = blockIdx.x;
    const int mt = bid >> 3, nt = bid & 7;
    const int wv = tid >> 6, lane = tid & 63;
    const int wm = wv & 1, wn = wv >> 1;
    const int ml = lane & 15, kg = lane >> 4;
    const int is64 = detect64(x);
    const int r = tid >> 1, kh = tid & 1;
    int tok = x[(mt*128 + r) << is64];
    tok = tok < 0 ? 0 : (tok >= VOCAB_ ? VOCAB_ - 1 : tok);
    const float* arow = emb + (size_t)tok * E_ + kh*16;
    const f16*   brow = wih + (size_t)(nt*128 + r) * E_ + kh*16;

    f32x4 acc[4][4] = {};
    for (int kk = 0; kk < 16; ++kk) {
        const int k0 = kk * 32;
        float4 a0 = *(const float4*)(arow + k0 + 0);
        float4 a1 = *(const float4*)(arow + k0 + 4);
        float4 a2 = *(const float4*)(arow + k0 + 8);
        float4 a3 = *(const float4*)(arow + k0 + 12);
        uint4 bu0 = *(const uint4*)(brow + k0);
        uint4 bu1 = *(const uint4*)(brow + k0 + 8);
        uint4 au0, au1;
        au0.x = pack2f(a0.x, a0.y); au0.y = pack2f(a0.z, a0.w);
        au0.z = pack2f(a1.x, a1.y); au0.w = pack2f(a1.z, a1.w);
        au1.x = pack2f(a2.x, a2.y); au1.y = pack2f(a2.z, a2.w);
        au1.z = pack2f(a3.x, a3.y); au1.w = pack2f(a3.z, a3.w);
        __syncthreads();
        *(uint4*)(&As[r*32 + kh*16 + 0]) = au0;
        *(uint4*)(&As[r*32 + kh*16 + 8]) = au1;
        *(uint4*)(&Bs[r*32 + kh*16 + 0]) = bu0;
        *(uint4*)(&Bs[r*32 + kh*16 + 8]) = bu1;
        __syncthreads();
        f16x8 af[4], bf[4];
        #pragma unroll
        for (int i = 0; i < 4; ++i) {
            af[i] = *(const f16x8*)(&As[(wm*64 + i*16 + ml)*32 + kg*8]);
            bf[i] = *(const f16x8*)(&Bs[(wn*64 + i*16 + ml)*32 + kg*8]);
        }
        #pragma unroll
        for (int i = 0; i < 4; ++i)
            #pragma unroll
            for (int j = 0; j < 4; ++j)
                acc[i][j] = __builtin_amdgcn_mfma_f32_16x16x32_f16(af[i], bf[j], acc[i][j], 0, 0, 0);
    }
    #pragma unroll
    for (int j = 0; j < 4; ++j) {
        const int gc = nt*128 + wn*64 + j*16 + ml;
        const float bs = bsum[gc];
        const int pc = ((gc & 255) << 2) | (gc >> 8);   // gate-interleaved column
        #pragma unroll
        for (int i = 0; i < 4; ++i) {
            #pragma unroll
            for (int q = 0; q < 4; ++q) {
                const int gr = mt*128 + wm*64 + i*16 + kg*4 + q;
                xg[(size_t)gr*G4_ + pc] = (f16)(acc[i][j][q] + bs);
            }
        }
    }
}

// ---------------- recurrence: 1 block = 1 batch ----------------
// 16 waves; thread (wv,lane): j = wv*16+(lane&15), kc = lane>>4.
// Owns rows {j, j+256, j+512, j+768} over k in [kc*64, kc*64+64).
// kc-partials reduced with 2 shfl_xor; c/h updated redundantly in all 4 kc lanes.
__global__ __launch_bounds__(1024, 4) void recur_k(
    const int* __restrict__ x, const f16* __restrict__ xg,
    const unsigned* __restrict__ wreg_g, const uint4* __restrict__ wlds_g,
    float* __restrict__ pool, float* __restrict__ lens)
{
    extern __shared__ char smem[];   // [0,131072): weights [wv][slot8][lane64]x16B
                                     // [131072, +1152): h double buffer, 4x144B each
    const int tid = threadIdx.x, b = blockIdx.x;
    const int wv = tid >> 6, lane = tid & 63, kc = lane >> 4, li = lane & 15;
    const int j = wv*16 + li;
    const int is64 = detect64(x);

    unsigned wr[96];
    #pragma unroll
    for (int i = 0; i < 96; ++i) wr[i] = wreg_g[i*1024 + tid];
    {
        uint4* wl = (uint4*)smem;
        #pragma unroll
        for (int s = 0; s < 8; ++s)
            wl[wv*512 + s*64 + lane] = wlds_g[wv*512 + s*64 + lane];
    }
    if (tid < 288) ((float*)(smem + HB_OFF))[tid] = 0.f;

    const int* xrow = x + (((size_t)b * T_) << is64);
    const char* xgrow = (const char*)xg + (size_t)b * T_ * 2048;
    const char* wbase = smem + wv*8192;
    float cst = 0.f, pooled = 0.f; int len = 0;
    __syncthreads();

    for (int t = 0; t < T_; ++t) {
        const char* hb = smem + HB_OFF + (t & 1)*576 + kc*144;
        uint2 xv = *(const uint2*)(xgrow + (size_t)t*2048 + j*8);
        float p[4] = {0.f, 0.f, 0.f, 0.f};
        // register-resident weights: 4 rows x 48 k
        #pragma unroll
        for (int cc = 0; cc < 6; ++cc) {
            uint4 hp = *(const uint4*)(hb + cc*16);
            #pragma unroll
            for (int q = 0; q < 4; ++q) {
                p[q] = fdot2u(wr[q*24 + cc*4 + 0], hp.x, p[q]);
                p[q] = fdot2u(wr[q*24 + cc*4 + 1], hp.y, p[q]);
                p[q] = fdot2u(wr[q*24 + cc*4 + 2], hp.z, p[q]);
                p[q] = fdot2u(wr[q*24 + cc*4 + 3], hp.w, p[q]);
            }
        }
        // LDS-resident weights: 4 rows x 16 k, conflict-free lane*16 layout
        #pragma unroll
        for (int kh = 0; kh < 2; ++kh) {
            uint4 hp = *(const uint4*)(hb + 96 + kh*16);
            #pragma unroll
            for (int q = 0; q < 4; ++q) {
                uint4 w4 = *(const uint4*)(wbase + (q*2 + kh)*1024 + lane*16);
                p[q] = fdot2u(w4.x, hp.x, p[q]);
                p[q] = fdot2u(w4.y, hp.y, p[q]);
                p[q] = fdot2u(w4.z, hp.z, p[q]);
                p[q] = fdot2u(w4.w, hp.w, p[q]);
            }
        }
        // reduce over kc (lane bits 4,5); all lanes end with full sums
        #pragma unroll
        for (int q = 0; q < 4; ++q) {
            p[q] += __shfl_xor(p[q], 16);
            p[q] += __shfl_xor(p[q], 32);
        }
        f16x2 x01 = __builtin_bit_cast(f16x2, xv.x);
        f16x2 x23 = __builtin_bit_cast(f16x2, xv.y);
        float ai = sigm (p[0] + (float)x01.x);
        float af = sigm (p[1] + (float)x01.y);
        float ag = tanhr(p[2] + (float)x23.x);
        float ao = sigm (p[3] + (float)x23.y);
        cst = af*cst + ai*ag;
        float hv = ao * tanhr(cst);
        if (kc == 0) {
            *(f16*)(smem + HB_OFF + ((t+1) & 1)*576 + (j >> 6)*144 + (j & 63)*2) = (f16)hv;
            if (xrow[(size_t)t << is64] != 0) { pooled += hv; ++len; }
        }
        __syncthreads();
    }
    if (kc == 0) pool[b*H_ + j] = pooled;
    if (tid == 0) lens[b] = (float)len;
}

// ---------------- head ----------------
__global__ __launch_bounds__(256) void head_k(
    const float* __restrict__ pool, const float* __restrict__ lens,
    const float* __restrict__ w1, const float* __restrict__ b1,
    const float* __restrict__ w2, const float* __restrict__ b2,
    float* __restrict__ out)
{
    __shared__ float pl[256];
    __shared__ float l1[512];
    const int b = blockIdx.x, tid = threadIdx.x;
    const float inv = 1.f / lens[b];
    pl[tid] = pool[b*256 + tid] * inv;
    __syncthreads();
    for (int o = tid; o < 512; o += 256) {
        const float4* wrow = (const float4*)(w1 + (size_t)o*256);
        float s = b1[o];
        #pragma unroll 8
        for (int k = 0; k < 64; ++k) {
            float4 wv = wrow[k];
            s += pl[k*4+0]*wv.x + pl[k*4+1]*wv.y + pl[k*4+2]*wv.z + pl[k*4+3]*wv.w;
        }
        l1[o] = fmaxf(s, 0.f);
    }
    __syncthreads();
    if (tid < 20) {
        const float4* wrow = (const float4*)(w2 + (size_t)tid*512);
        float s = b2[tid];
        #pragma unroll 8
        for (int k = 0; k < 128; ++k) {
            float4 wv = wrow[k];
            s += l1[k*4+0]*wv.x + l1[k*4+1]*wv.y + l1[k*4+2]*wv.z + l1[k*4+3]*wv.w;
        }
        out[b*20 + tid] = s;
    }
}

extern "C" void kernel_launch(void* const* d_in, const int* in_sizes, int n_in,
                              void* d_out, int out_size, void* d_ws, size_t ws_size,
                              hipStream_t stream) {
    (void)in_sizes; (void)n_in; (void)out_size; (void)ws_size;
    const int*   x    = (const int*)d_in[0];
    const float* emb  = (const float*)d_in[1];
    const float* w_ih = (const float*)d_in[2];
    const float* w_hh = (const float*)d_in[3];
    const float* b_ih = (const float*)d_in[4];
    const float* b_hh = (const float*)d_in[5];
    const float* w1   = (const float*)d_in[6];
    const float* b1   = (const float*)d_in[7];
    const float* w2   = (const float*)d_in[8];
    const float* b2   = (const float*)d_in[9];
    float* out = (float*)d_out;
    char* ws = (char*)d_ws;

    f16*      xg    = (f16*)(ws + WS_XG);
    f16*      wih16 = (f16*)(ws + WS_WIH);
    unsigned* wreg  = (unsigned*)(ws + WS_WREG);
    uint4*    wlds  = (uint4*)(ws + WS_WLDS);
    float*    bsum  = (float*)(ws + WS_BSUM);
    float*    pool  = (float*)(ws + WS_POOL);
    float*    lensb = (float*)(ws + WS_LENS);

    hipLaunchKernelGGL(prep_k, dim3(512), dim3(256), 0, stream,
                       w_ih, w_hh, b_ih, b_hh, wih16, wreg, wlds, bsum);
    hipLaunchKernelGGL(gemm_xg_k, dim3(4096), dim3(256), 0, stream,
                       x, emb, wih16, bsum, xg);
    hipLaunchKernelGGL(recur_k, dim3(32), dim3(1024), LDS_BYTES, stream,
                       x, xg, wreg, wlds, pool, lensb);
    hipLaunchKernelGGL(head_k, dim3(32), dim3(256), 0, stream,
                       pool, lensb, w1, b1, w2, b2, out);
}

// Round 3
// 3738.174 us; speedup vs baseline: 1.5908x; 1.3288x over previous
//
#include <hip/hip_runtime.h>
#include <hip/hip_fp16.h>

typedef _Float16 f16;
typedef _Float16 f16x2 __attribute__((ext_vector_type(2)));
typedef _Float16 f16x8 __attribute__((ext_vector_type(8)));
typedef float f32x4 __attribute__((ext_vector_type(4)));

#define B_    32
#define T_    2048
#define E_    512
#define H_    256
#define G4_   1024
#define VOCAB_ 50257

// ---------------- workspace layout (bytes) ----------------
static const size_t WS_XG   = 0;            // f16 [65536][1024] = 134217728
static const size_t WS_WIH  = 134217728ull; // f16 [1024][512]   = 1048576
static const size_t WS_WREG = 135266304ull; // u32 [192][512]    = 393216
static const size_t WS_WLDS = 135659520ull; // uint4 [8*16*64]   = 131072
static const size_t WS_BSUM = 135790592ull; // f32 [1024]
static const size_t WS_POOL = 135794688ull; // f32 [32][256]
static const size_t WS_LENS = 135827456ull; // f32 [32]

#define HB_OFF 131072                 // h double-buffer inside dynamic LDS
#define LDS_BYTES (131072 + 1088)     // weights + 2 x 544B h buffers

__device__ __forceinline__ unsigned pack2f(float a, float b) {
    f16x2 h; h.x = (f16)a; h.y = (f16)b;
    return __builtin_bit_cast(unsigned, h);
}

__device__ __forceinline__ float fdot2u(unsigned a, unsigned b, float c) {
#if __has_builtin(__builtin_amdgcn_fdot2)
    return __builtin_amdgcn_fdot2(__builtin_bit_cast(f16x2, a),
                                  __builtin_bit_cast(f16x2, b), c, false);
#else
    f16x2 av = __builtin_bit_cast(f16x2, a), bv = __builtin_bit_cast(f16x2, b);
    return c + (float)av.x * (float)bv.x + (float)av.y * (float)bv.y;
#endif
}

__device__ __forceinline__ float sigm(float v) {
    return 1.f / (1.f + exp2f(-1.44269504f * v));
}
__device__ __forceinline__ float tanhr(float v) {
    float t = exp2f(-2.88539008f * fabsf(v));   // e^(-2|v|)
    float r = (1.f - t) / (1.f + t);
    return v < 0.f ? -r : r;
}

__device__ __forceinline__ int detect64(const int* x) {
    return (x[1] == 0 && x[3] == 0 && x[5] == 0) ? 1 : 0;
}

// ---------------- prep: weight conversions + recurrence layouts ----------------
// recur mapping: tid -> wv=tid>>6, lane=tid&63, kc=lane&1, li=lane>>1, j=wv*32+li.
// Thread owns rows {q*256+j, q=0..3}, k in [kc*128, kc*128+128).
// Register part: k in [kc*128, +96): wr[q*48+cc*4+u] <- k = kc*128+cc*8+u*2.
// LDS part:      k in [kc*128+96, +32): slot s=q*4+e covers k = kc*128+96+e*8.
__global__ void prep_k(const float* __restrict__ w_ih, const float* __restrict__ w_hh,
                       const float* __restrict__ b_ih, const float* __restrict__ b_hh,
                       f16* __restrict__ wih16, unsigned* __restrict__ wreg,
                       uint4* __restrict__ wlds, float* __restrict__ bsum)
{
    const int gid = blockIdx.x * blockDim.x + threadIdx.x;
    const int stride = gridDim.x * blockDim.x;
    for (int i = gid; i < G4_*E_; i += stride) wih16[i] = (f16)w_ih[i];
    for (int i = gid; i < G4_; i += stride) bsum[i] = b_ih[i] + b_hh[i];
    for (int n = gid; n < 192*512; n += stride) {
        const int ii = n >> 9, t = n & 511;
        const int wv = t >> 6, lane = t & 63, kc = lane & 1, li = lane >> 1;
        const int j = wv*32 + li;
        const int q = ii / 48, rem = ii % 48, cc = rem >> 2, u = rem & 3;
        const int row = q*256 + j;
        const int k = kc*128 + cc*8 + u*2;
        wreg[n] = pack2f(w_hh[row*256 + k], w_hh[row*256 + k + 1]);
    }
    for (int m = gid; m < 8*16*64; m += stride) {
        const int lane = m & 63, s = (m >> 6) & 15, wv = m >> 10;
        const int kc = lane & 1, li = lane >> 1;
        const int j = wv*32 + li;
        const int q = s >> 2, e = s & 3;
        const int row = q*256 + j;
        const int kb = kc*128 + 96 + e*8;
        uint4 v;
        v.x = pack2f(w_hh[row*256 + kb + 0], w_hh[row*256 + kb + 1]);
        v.y = pack2f(w_hh[row*256 + kb + 2], w_hh[row*256 + kb + 3]);
        v.z = pack2f(w_hh[row*256 + kb + 4], w_hh[row*256 + kb + 5]);
        v.w = pack2f(w_hh[row*256 + kb + 6], w_hh[row*256 + kb + 7]);
        wlds[m] = v;
    }
}

// ---------------- GEMM: xg[t][j*4+gt] = (f16(emb[x]) @ f16(w_ih)^T + bsum) permuted ----------------
__global__ __launch_bounds__(256) void gemm_xg_k(
    const int* __restrict__ x, const float* __restrict__ emb,
    const f16* __restrict__ wih, const float* __restrict__ bsum,
    f16* __restrict__ xg)
{
    __shared__ f16 As[128*32];
    __shared__ f16 Bs[128*32];
    const int tid = threadIdx.x;
    const int bid = blockIdx.x;
    const int mt = bid >> 3, nt = bid & 7;
    const int wv = tid >> 6, lane = tid & 63;
    const int wm = wv & 1, wn = wv >> 1;
    const int ml = lane & 15, kg = lane >> 4;
    const int is64 = detect64(x);
    const int r = tid >> 1, kh = tid & 1;
    int tok = x[(mt*128 + r) << is64];
    tok = tok < 0 ? 0 : (tok >= VOCAB_ ? VOCAB_ - 1 : tok);
    const float* arow = emb + (size_t)tok * E_ + kh*16;
    const f16*   brow = wih + (size_t)(nt*128 + r) * E_ + kh*16;

    f32x4 acc[4][4] = {};
    for (int kk = 0; kk < 16; ++kk) {
        const int k0 = kk * 32;
        float4 a0 = *(const float4*)(arow + k0 + 0);
        float4 a1 = *(const float4*)(arow + k0 + 4);
        float4 a2 = *(const float4*)(arow + k0 + 8);
        float4 a3 = *(const float4*)(arow + k0 + 12);
        uint4 bu0 = *(const uint4*)(brow + k0);
        uint4 bu1 = *(const uint4*)(brow + k0 + 8);
        uint4 au0, au1;
        au0.x = pack2f(a0.x, a0.y); au0.y = pack2f(a0.z, a0.w);
        au0.z = pack2f(a1.x, a1.y); au0.w = pack2f(a1.z, a1.w);
        au1.x = pack2f(a2.x, a2.y); au1.y = pack2f(a2.z, a2.w);
        au1.z = pack2f(a3.x, a3.y); au1.w = pack2f(a3.z, a3.w);
        __syncthreads();
        *(uint4*)(&As[r*32 + kh*16 + 0]) = au0;
        *(uint4*)(&As[r*32 + kh*16 + 8]) = au1;
        *(uint4*)(&Bs[r*32 + kh*16 + 0]) = bu0;
        *(uint4*)(&Bs[r*32 + kh*16 + 8]) = bu1;
        __syncthreads();
        f16x8 af[4], bf[4];
        #pragma unroll
        for (int i = 0; i < 4; ++i) {
            af[i] = *(const f16x8*)(&As[(wm*64 + i*16 + ml)*32 + kg*8]);
            bf[i] = *(const f16x8*)(&Bs[(wn*64 + i*16 + ml)*32 + kg*8]);
        }
        #pragma unroll
        for (int i = 0; i < 4; ++i)
            #pragma unroll
            for (int j = 0; j < 4; ++j)
                acc[i][j] = __builtin_amdgcn_mfma_f32_16x16x32_f16(af[i], bf[j], acc[i][j], 0, 0, 0);
    }
    #pragma unroll
    for (int j = 0; j < 4; ++j) {
        const int gc = nt*128 + wn*64 + j*16 + ml;
        const float bs = bsum[gc];
        const int pc = ((gc & 255) << 2) | (gc >> 8);   // gate-interleaved column
        #pragma unroll
        for (int i = 0; i < 4; ++i) {
            #pragma unroll
            for (int q = 0; q < 4; ++q) {
                const int gr = mt*128 + wm*64 + i*16 + kg*4 + q;
                xg[(size_t)gr*G4_ + pc] = (f16)(acc[i][j][q] + bs);
            }
        }
    }
}

// ---------------- recurrence: 1 block = 1 batch, 512 threads, 2 waves/SIMD ----------------
// Thread (wv,lane): j = wv*32 + (lane>>1), kc = lane&1.
// Owns rows {j, j+256, j+512, j+768} over k in [kc*128, kc*128+128):
//   96 k from wr[192] (VGPR-resident), 32 k from LDS.
// kc-partials reduced with one quad shfl_xor; c/h updated redundantly in both lanes.
__global__ __launch_bounds__(512) __attribute__((amdgpu_waves_per_eu(2, 2)))
void recur_k(
    const int* __restrict__ x, const f16* __restrict__ xg,
    const unsigned* __restrict__ wreg_g, const uint4* __restrict__ wlds_g,
    float* __restrict__ pool, float* __restrict__ lens)
{
    extern __shared__ char smem[];   // [0,131072): weights [wv][slot16][lane64]x16B
                                     // [131072,+1088): h double buffer, 2 x (2 x 272B)
    const int tid = threadIdx.x, b = blockIdx.x;
    const int wv = tid >> 6, lane = tid & 63, kc = lane & 1, li = lane >> 1;
    const int j = wv*32 + li;
    const int is64 = detect64(x);

    unsigned wr[192];
    #pragma unroll
    for (int i = 0; i < 192; ++i) wr[i] = wreg_g[i*512 + tid];
    {
        uint4* wl = (uint4*)smem;
        #pragma unroll
        for (int s = 0; s < 16; ++s)
            wl[wv*1024 + s*64 + lane] = wlds_g[wv*1024 + s*64 + lane];
    }
    if (tid < 272) ((unsigned*)(smem + HB_OFF))[tid] = 0u;

    const int* xrow = x + (((size_t)b * T_) << is64);
    const char* xgrow = (const char*)xg + (size_t)b * T_ * 2048;
    const char* wbase = smem + wv*16384;
    float cst = 0.f, pooled = 0.f; int len = 0;
    __syncthreads();

    for (int t = 0; t < T_; ++t) {
        const char* hb = smem + HB_OFF + (t & 1)*544 + kc*272;
        uint2 xv = *(const uint2*)(xgrow + (size_t)t*2048 + j*8);
        const int tokm = xrow[(size_t)t << is64];
        float p[4] = {0.f, 0.f, 0.f, 0.f};
        // register-resident weights: 4 rows x 96 k
        #pragma unroll
        for (int cc = 0; cc < 12; ++cc) {
            uint4 hp = *(const uint4*)(hb + cc*16);
            #pragma unroll
            for (int q = 0; q < 4; ++q) {
                p[q] = fdot2u(wr[q*48 + cc*4 + 0], hp.x, p[q]);
                p[q] = fdot2u(wr[q*48 + cc*4 + 1], hp.y, p[q]);
                p[q] = fdot2u(wr[q*48 + cc*4 + 2], hp.z, p[q]);
                p[q] = fdot2u(wr[q*48 + cc*4 + 3], hp.w, p[q]);
            }
        }
        // LDS-resident weights: 4 rows x 32 k, dense lane*16 layout
        #pragma unroll
        for (int e = 0; e < 4; ++e) {
            uint4 hp = *(const uint4*)(hb + 192 + e*16);
            #pragma unroll
            for (int q = 0; q < 4; ++q) {
                uint4 w4 = *(const uint4*)(wbase + ((q*4 + e)*64 + lane)*16);
                p[q] = fdot2u(w4.x, hp.x, p[q]);
                p[q] = fdot2u(w4.y, hp.y, p[q]);
                p[q] = fdot2u(w4.z, hp.z, p[q]);
                p[q] = fdot2u(w4.w, hp.w, p[q]);
            }
        }
        // reduce over kc (lane bit 0) -> both lanes hold full sums
        #pragma unroll
        for (int q = 0; q < 4; ++q) p[q] += __shfl_xor(p[q], 1);

        f16x2 x01 = __builtin_bit_cast(f16x2, xv.x);
        f16x2 x23 = __builtin_bit_cast(f16x2, xv.y);
        float ai = sigm (p[0] + (float)x01.x);
        float af = sigm (p[1] + (float)x01.y);
        float ag = tanhr(p[2] + (float)x23.x);
        float ao = sigm (p[3] + (float)x23.y);
        cst = af*cst + ai*ag;
        float hv = ao * tanhr(cst);
        if (kc == 0) {
            *(f16*)(smem + HB_OFF + ((t+1) & 1)*544 + (j >> 7)*272 + (j & 127)*2) = (f16)hv;
            if (tokm != 0) { pooled += hv; ++len; }
        }
        __syncthreads();
    }
    if (kc == 0) pool[b*H_ + j] = pooled;
    if (tid == 0) lens[b] = (float)len;
}

// ---------------- head ----------------
__global__ __launch_bounds__(256) void head_k(
    const float* __restrict__ pool, const float* __restrict__ lens,
    const float* __restrict__ w1, const float* __restrict__ b1,
    const float* __restrict__ w2, const float* __restrict__ b2,
    float* __restrict__ out)
{
    __shared__ float pl[256];
    __shared__ float l1[512];
    const int b = blockIdx.x, tid = threadIdx.x;
    const float inv = 1.f / lens[b];
    pl[tid] = pool[b*256 + tid] * inv;
    __syncthreads();
    for (int o = tid; o < 512; o += 256) {
        const float4* wrow = (const float4*)(w1 + (size_t)o*256);
        float s = b1[o];
        #pragma unroll 8
        for (int k = 0; k < 64; ++k) {
            float4 wv = wrow[k];
            s += pl[k*4+0]*wv.x + pl[k*4+1]*wv.y + pl[k*4+2]*wv.z + pl[k*4+3]*wv.w;
        }
        l1[o] = fmaxf(s, 0.f);
    }
    __syncthreads();
    if (tid < 20) {
        const float4* wrow = (const float4*)(w2 + (size_t)tid*512);
        float s = b2[tid];
        #pragma unroll 8
        for (int k = 0; k < 128; ++k) {
            float4 wv = wrow[k];
            s += l1[k*4+0]*wv.x + l1[k*4+1]*wv.y + l1[k*4+2]*wv.z + l1[k*4+3]*wv.w;
        }
        out[b*20 + tid] = s;
    }
}

extern "C" void kernel_launch(void* const* d_in, const int* in_sizes, int n_in,
                              void* d_out, int out_size, void* d_ws, size_t ws_size,
                              hipStream_t stream) {
    (void)in_sizes; (void)n_in; (void)out_size; (void)ws_size;
    const int*   x    = (const int*)d_in[0];
    const float* emb  = (const float*)d_in[1];
    const float* w_ih = (const float*)d_in[2];
    const float* w_hh = (const float*)d_in[3];
    const float* b_ih = (const float*)d_in[4];
    const float* b_hh = (const float*)d_in[5];
    const float* w1   = (const float*)d_in[6];
    const float* b1   = (const float*)d_in[7];
    const float* w2   = (const float*)d_in[8];
    const float* b2   = (const float*)d_in[9];
    float* out = (float*)d_out;
    char* ws = (char*)d_ws;

    f16*      xg    = (f16*)(ws + WS_XG);
    f16*      wih16 = (f16*)(ws + WS_WIH);
    unsigned* wreg  = (unsigned*)(ws + WS_WREG);
    uint4*    wlds  = (uint4*)(ws + WS_WLDS);
    float*    bsum  = (float*)(ws + WS_BSUM);
    float*    pool  = (float*)(ws + WS_POOL);
    float*    lensb = (float*)(ws + WS_LENS);

    hipLaunchKernelGGL(prep_k, dim3(512), dim3(256), 0, stream,
                       w_ih, w_hh, b_ih, b_hh, wih16, wreg, wlds, bsum);
    hipLaunchKernelGGL(gemm_xg_k, dim3(4096), dim3(256), 0, stream,
                       x, emb, wih16, bsum, xg);
    hipLaunchKernelGGL(recur_k, dim3(32), dim3(512), LDS_BYTES, stream,
                       x, xg, wreg, wlds, pool, lensb);
    hipLaunchKernelGGL(head_k, dim3(32), dim3(256), 0, stream,
                       pool, lensb, w1, b1, w2, b2, out);
}